// Round 1
// baseline (462.087 us; speedup 1.0000x reference)
//
#include <hip/hip_runtime.h>
#include <stdint.h>

// SparseConv2D: out[f, hw] = relu(sum_c K[f,c] * X[c, hw] + bias[f])
// F=C=512, HW=65536, K ~10% dense (stored dense with zeros; mask redundant).
//
// Strategy: device-side ELL build (kernel!=0) + LDS-staged bf16 X strips.
//   - prep_ell: 1 wave/filter, ballot-compaction -> (c*64, w) int2 pairs in d_ws.
//   - spmm_main: block=1024 (16 waves), strip=128 hw, all 512 channels staged
//     as packed bf16x2 in 128 KiB LDS (1 block/CU). Wave owns 32 filters;
//     inner loop: 1 ds_read_b32 (2 hw) + unpack + 2 fma. Conflict-free banks.

#define NF 512
#define NC 512
#define HW 65536
#define ELL_CAP 96      // 6.6 sigma above mean row nnz (51.2, sd 6.8)
#define ELL_STRIDE 104  // cap + terminator + pad
#define STRIP 128

__device__ __forceinline__ uint32_t f32_to_bf16_rne(float x) {
  uint32_t u = __float_as_uint(x);
  return (u + 0x7fffu + ((u >> 16) & 1u)) >> 16;
}

__global__ __launch_bounds__(256) void prep_ell(const float* __restrict__ kernel,
                                                int2* __restrict__ ell,
                                                int* __restrict__ cnt) {
  const int row = (blockIdx.x * 256 + threadIdx.x) >> 6;  // one wave per filter
  const int lane = threadIdx.x & 63;
  if (row >= NF) return;
  const float* krow = kernel + (size_t)row * NC;
  int2* erow = ell + (size_t)row * ELL_STRIDE;
  int n = 0;
  for (int step = 0; step < NC / 64; ++step) {
    const int c = step * 64 + lane;
    const float w = krow[c];                      // coalesced
    const bool nz = (w != 0.0f);
    const unsigned long long m = __ballot(nz);
    const int pos = n + __popcll(m & ((1ull << lane) - 1ull));
    if (nz && pos < ELL_CAP) erow[pos] = make_int2(c << 6, __float_as_int(w));
    n += __popcll(m);
  }
  if (lane == 0) {
    const int nn = n < ELL_CAP ? n : ELL_CAP;
    cnt[row] = nn;
    erow[nn] = make_int2(0, 0);  // terminator: safe branch-free prefetch
  }
}

__global__ __launch_bounds__(1024, 1) void spmm_main(
    const float* __restrict__ X, const int2* __restrict__ ell,
    const int* __restrict__ cnt, const float* __restrict__ bias,
    float* __restrict__ out) {
  // 512 rows x 64 u32 (each u32 = 2 bf16 = 2 hw) = 128 KiB
  __shared__ uint32_t lds[NC * (STRIP / 2)];

  const int tid = threadIdx.x;
  const int wave = tid >> 6;  // 0..15
  const int lane = tid & 63;
  const int hw0 = blockIdx.x * STRIP;

  // ---- stage: each wave loads 32 channel rows, converts fp32 -> bf16x2 ----
  {
    const int r0 = wave * 32;
    for (int i = 0; i < 32; ++i) {
      const int r = r0 + i;
      const float2 x2 = ((const float2*)(X + (size_t)r * HW + hw0))[lane];
      const uint32_t lo = f32_to_bf16_rne(x2.x);
      const uint32_t hi = f32_to_bf16_rne(x2.y);
      lds[r * 64 + lane] = lo | (hi << 16);
    }
  }
  __syncthreads();

  // ---- compute: each wave owns 32 filters; lane owns hw pair (2*lane, 2*lane+1)
  const int f0 = wave * 32;
  for (int fi = 0; fi < 32; ++fi) {
    const int f = f0 + fi;
    const int n = cnt[f];  // wave-uniform
    const int2* e = ell + (size_t)f * ELL_STRIDE;
    int2 nxt = e[0];  // software-pipelined ELL entry prefetch
    float ax = 0.f, ay = 0.f;
    for (int k = 0; k < n; ++k) {
      const int2 cur = nxt;
      nxt = e[k + 1];  // terminator makes k+1==n safe
      const uint32_t u = lds[cur.x + lane];  // bank = lane%32, conflict-free
      const float w = __int_as_float(cur.y);
      ax = fmaf(w, __uint_as_float(u << 16), ax);
      ay = fmaf(w, __uint_as_float(u & 0xffff0000u), ay);
    }
    const float b = bias[f];
    float2 o;
    o.x = fmaxf(ax + b, 0.f);
    o.y = fmaxf(ay + b, 0.f);
    ((float2*)(out + (size_t)f * HW + hw0))[lane] = o;  // coalesced 512B/wave
  }
}

extern "C" void kernel_launch(void* const* d_in, const int* in_sizes, int n_in,
                              void* d_out, int out_size, void* d_ws, size_t ws_size,
                              hipStream_t stream) {
  const float* X = (const float*)d_in[0];     // (1, 512, 256, 256) fp32
  const float* kern = (const float*)d_in[1];  // (512, 512) fp32, pre-masked
  // d_in[2] = mask: redundant (kernel already has zeros where mask is false)
  const float* bias = (const float*)d_in[3];  // (512,) fp32
  float* out = (float*)d_out;

  int2* ell = (int2*)d_ws;
  int* cnt = (int*)((char*)d_ws + (size_t)NF * ELL_STRIDE * sizeof(int2));

  prep_ell<<<NF * 64 / 256, 256, 0, stream>>>(kern, ell, cnt);
  spmm_main<<<HW / STRIP, 1024, 0, stream>>>(X, ell, cnt, bias, out);
}

// Round 2
// 330.205 us; speedup vs baseline: 1.3994x; 1.3994x over previous
//
#include <hip/hip_runtime.h>
#include <stdint.h>

// SparseConv2D: out[f, hw] = relu(sum_c K[f,c] * X[c, hw] + bias[f])
// F=C=512, HW=65536, K ~10% dense. ELL build + LDS-staged bf16 X strips.
//
// R2: ds_read_b128 inner loop (8 hw/lane/read), 8 lane-groups x 4 filters,
// STRIP=64 (64 KiB LDS -> 2 blocks/CU), quad-entry int4 prefetch,
// wave-uniform loop bound over zero-padded ELL rows.

#define NF 512
#define NC 512
#define HW 65536
#define ELL_CAP 96      // 6.6 sigma above mean row nnz (51.2, sd 6.8)
#define ELL_STRIDE 104  // 16B-aligned rows (104*8 = 832 = 52*16)
#define STRIP 64

__device__ __forceinline__ uint32_t f32_to_bf16_rne(float x) {
  uint32_t u = __float_as_uint(x);
  return (u + 0x7fffu + ((u >> 16) & 1u)) >> 16;
}
__device__ __forceinline__ float blo(uint32_t u) { return __uint_as_float(u << 16); }
__device__ __forceinline__ float bhi(uint32_t u) { return __uint_as_float(u & 0xffff0000u); }

__global__ __launch_bounds__(256) void prep_ell(const float* __restrict__ kernel,
                                                int2* __restrict__ ell,
                                                int* __restrict__ cnt) {
  const int row = (blockIdx.x * 256 + threadIdx.x) >> 6;  // one wave per filter
  const int lane = threadIdx.x & 63;
  if (row >= NF) return;
  const float* krow = kernel + (size_t)row * NC;
  int2* erow = ell + (size_t)row * ELL_STRIDE;
  int n = 0;
  for (int step = 0; step < NC / 64; ++step) {
    const int c = step * 64 + lane;
    const float w = krow[c];  // coalesced
    const bool nz = (w != 0.0f);
    const unsigned long long m = __ballot(nz);
    const int pos = n + __popcll(m & ((1ull << lane) - 1ull));
    // store byte row-offset: c * (STRIP bf16 * 2B) = c*128
    if (nz && pos < ELL_CAP) erow[pos] = make_int2(c << 7, __float_as_int(w));
    n += __popcll(m);
  }
  const int nn = n < ELL_CAP ? n : ELL_CAP;
  // zero-pad tail: over-run iterations become fma * 0 on row 0 (harmless)
  for (int p = nn + lane; p < ELL_STRIDE; p += 64) erow[p] = make_int2(0, 0);
  if (lane == 0) cnt[row] = nn;
}

__global__ __launch_bounds__(1024, 8) void spmm_main(
    const float* __restrict__ X, const int2* __restrict__ ell,
    const int* __restrict__ cnt, const float* __restrict__ bias,
    float* __restrict__ out) {
  // 512 rows x 64 bf16 (32 u32) = 64 KiB -> 2 blocks/CU
  __shared__ uint32_t lds[NC * (STRIP / 2)];

  const int tid = threadIdx.x;
  const int wave = tid >> 6;  // 0..15
  const int lane = tid & 63;
  const int hw0 = blockIdx.x * STRIP;

  // ---- stage: wave w loads rows [w*32, w*32+32); 4 rows per float4 round ----
  // lanes 0-15 -> row base+0, 16-31 -> +1, ... : 4x 256B contiguous segments.
  {
    const int rsub = lane >> 4;          // 0..3
    const int col = (lane & 15) * 4;     // float index within 64-wide row
    for (int i = 0; i < 8; ++i) {
      const int r = wave * 32 + i * 4 + rsub;
      const float4 x4 = *(const float4*)(X + (size_t)r * HW + hw0 + col);
      uint2 p;
      p.x = f32_to_bf16_rne(x4.x) | (f32_to_bf16_rne(x4.y) << 16);
      p.y = f32_to_bf16_rne(x4.z) | (f32_to_bf16_rne(x4.w) << 16);
      *(uint2*)((char*)lds + r * 128 + col * 2) = p;  // ds_write_b64
    }
  }
  __syncthreads();

  // ---- compute: 8 groups of 8 lanes; group g owns filters f0+g*4+fi ----
  const int l8 = lane & 7;
  const int g = lane >> 3;
  const int lbase = l8 * 16;  // byte offset within 128B row (8 bf16 per lane)
  const int f0 = wave * 32;

  for (int fi = 0; fi < 4; ++fi) {
    const int f = f0 + g * 4 + fi;
    int n = cnt[f];
    n = max(n, __shfl_xor(n, 8));
    n = max(n, __shfl_xor(n, 16));
    n = max(n, __shfl_xor(n, 32));  // wave-uniform bound (zero-pad makes it safe)
    const int quads = (n + 3) >> 2;
    const int4* e4 = (const int4*)(ell + (size_t)f * ELL_STRIDE);
    int4 pA = e4[0], pB = e4[1];  // 2 entries per int4; prefetch one quad ahead
    float a0 = 0.f, a1 = 0.f, a2 = 0.f, a3 = 0.f;
    float a4 = 0.f, a5 = 0.f, a6 = 0.f, a7 = 0.f;

#define PROC(OFF, WB)                                                   \
    {                                                                   \
      const uint4 u = *(const uint4*)((const char*)lds + (OFF) + lbase);\
      const float w = __int_as_float(WB);                               \
      a0 = fmaf(w, blo(u.x), a0); a1 = fmaf(w, bhi(u.x), a1);           \
      a2 = fmaf(w, blo(u.y), a2); a3 = fmaf(w, bhi(u.y), a3);           \
      a4 = fmaf(w, blo(u.z), a4); a5 = fmaf(w, bhi(u.z), a5);           \
      a6 = fmaf(w, blo(u.w), a6); a7 = fmaf(w, bhi(u.w), a7);           \
    }

    for (int q = 0; q < quads; ++q) {
      const int4 cA = pA, cB = pB;
      pA = e4[q * 2 + 2];  // stays within 104-entry padded row (<= idx 51)
      pB = e4[q * 2 + 3];
      PROC(cA.x, cA.y);
      PROC(cA.z, cA.w);
      PROC(cB.x, cB.y);
      PROC(cB.z, cB.w);
    }
#undef PROC

    const float b = bias[f];
    float4 o0, o1;
    o0.x = fmaxf(a0 + b, 0.f); o0.y = fmaxf(a1 + b, 0.f);
    o0.z = fmaxf(a2 + b, 0.f); o0.w = fmaxf(a3 + b, 0.f);
    o1.x = fmaxf(a4 + b, 0.f); o1.y = fmaxf(a5 + b, 0.f);
    o1.z = fmaxf(a6 + b, 0.f); o1.w = fmaxf(a7 + b, 0.f);
    float* op = out + (size_t)f * HW + hw0 + l8 * 8;
    *(float4*)op = o0;
    *(float4*)(op + 4) = o1;
  }
}

extern "C" void kernel_launch(void* const* d_in, const int* in_sizes, int n_in,
                              void* d_out, int out_size, void* d_ws, size_t ws_size,
                              hipStream_t stream) {
  const float* X = (const float*)d_in[0];     // (1, 512, 256, 256) fp32
  const float* kern = (const float*)d_in[1];  // (512, 512) fp32, pre-masked
  // d_in[2] = mask: redundant (kernel already zeroed where mask false)
  const float* bias = (const float*)d_in[3];  // (512,) fp32
  float* out = (float*)d_out;

  int2* ell = (int2*)d_ws;
  int* cnt = (int*)((char*)d_ws + (size_t)NF * ELL_STRIDE * sizeof(int2));

  prep_ell<<<NF * 64 / 256, 256, 0, stream>>>(kern, ell, cnt);
  spmm_main<<<HW / STRIP, 1024, 0, stream>>>(X, ell, cnt, bias, out);
}

// Round 4
// 329.583 us; speedup vs baseline: 1.4020x; 1.0019x over previous
//
#include <hip/hip_runtime.h>
#include <stdint.h>

// SparseConv2D: out[f, hw] = relu(sum_c K[f,c] * X[c, hw] + bias[f])
// F=C=512, HW=65536, K ~10% dense. ELL build + LDS-staged f16 X strips.
//
// R4 (= R3 with type fix): X staged as packed f16 (cvt_pkrtz) -> inner loop is
// v_fma_mix_f32 (1 VALU/MAC, no unpack). Row stride 144B (+16 pad) de-aliases
// the 8 lane-groups' bank-quads. STRIP=64, 72 KiB LDS -> 2 blocks/CU.
// half2_t must be __fp16 ext_vector (cvt_pkrtz's return type), not _Float16.

#define NF 512
#define NC 512
#define HW 65536
#define ELL_CAP 96      // 6.6 sigma above mean row nnz (51.2, sd 6.8)
#define ELL_STRIDE 104  // 16B-aligned rows of int2
#define STRIP 64
#define ROWB 144        // 128B f16 data + 16B pad: banks de-aliased per row

typedef __fp16 half2_t __attribute__((ext_vector_type(2)));

__global__ __launch_bounds__(256) void prep_ell(const float* __restrict__ kernel,
                                                int2* __restrict__ ell,
                                                int* __restrict__ cnt) {
  const int row = (blockIdx.x * 256 + threadIdx.x) >> 6;  // one wave per filter
  const int lane = threadIdx.x & 63;
  if (row >= NF) return;
  const float* krow = kernel + (size_t)row * NC;
  int2* erow = ell + (size_t)row * ELL_STRIDE;
  int n = 0;
  for (int step = 0; step < NC / 64; ++step) {
    const int c = step * 64 + lane;
    const float w = krow[c];  // coalesced
    const bool nz = (w != 0.0f);
    const unsigned long long m = __ballot(nz);
    const int pos = n + __popcll(m & ((1ull << lane) - 1ull));
    if (nz && pos < ELL_CAP) erow[pos] = make_int2(c * ROWB, __float_as_int(w));
    n += __popcll(m);
  }
  const int nn = n < ELL_CAP ? n : ELL_CAP;
  // zero-pad tail: overrun iterations do fma * 0.0 on row 0 (finite) -> harmless
  for (int p = nn + lane; p < ELL_STRIDE; p += 64) erow[p] = make_int2(0, 0);
  if (lane == 0) cnt[row] = nn;
}

__global__ __launch_bounds__(1024, 8) void spmm_main(
    const float* __restrict__ X, const int2* __restrict__ ell,
    const int* __restrict__ cnt, const float* __restrict__ bias,
    float* __restrict__ out) {
  // 512 rows x 144B (64 f16 + pad) = 72 KiB -> 2 blocks/CU
  __shared__ __align__(16) char ldsb[NC * ROWB];

  const int tid = threadIdx.x;
  const int wave = tid >> 6;  // 0..15
  const int lane = tid & 63;
  const int hw0 = blockIdx.x * STRIP;

  // ---- stage: wave w loads rows [w*32, w*32+32); fp32 -> packed f16 (RTZ) ----
  {
    const int rsub = lane >> 4;       // 0..3
    const int col = (lane & 15) * 4;  // float index within 64-wide row
    for (int i = 0; i < 8; ++i) {
      const int r = wave * 32 + i * 4 + rsub;
      const float4 x4 = *(const float4*)(X + (size_t)r * HW + hw0 + col);
      const half2_t p0 = __builtin_amdgcn_cvt_pkrtz(x4.x, x4.y);
      const half2_t p1 = __builtin_amdgcn_cvt_pkrtz(x4.z, x4.w);
      uint2 p;
      p.x = __builtin_bit_cast(uint32_t, p0);
      p.y = __builtin_bit_cast(uint32_t, p1);
      *(uint2*)(ldsb + r * ROWB + col * 2) = p;  // ds_write_b64, 8B aligned
    }
  }
  __syncthreads();

  // ---- compute: 8 groups of 8 lanes; group g owns filters wave*32+g*4+fi ----
  const int l8 = lane & 7;
  const int g = lane >> 3;
  const int lbase = l8 * 16;  // byte offset in row: 8 f16 = hw [l8*8, l8*8+8)

  for (int fi = 0; fi < 4; ++fi) {
    const int f = wave * 32 + g * 4 + fi;
    int n = cnt[f];
    n = max(n, __shfl_xor(n, 8));
    n = max(n, __shfl_xor(n, 16));
    n = max(n, __shfl_xor(n, 32));  // wave-uniform bound; zero-pad makes it safe
    const int quads = (n + 3) >> 2;
    const int4* e4 = (const int4*)(ell + (size_t)f * ELL_STRIDE);
    int4 pA = e4[0], pB = e4[1];  // 2 entries per int4; prefetch one quad ahead
    float a0 = 0.f, a1 = 0.f, a2 = 0.f, a3 = 0.f;
    float a4 = 0.f, a5 = 0.f, a6 = 0.f, a7 = 0.f;

#define PROC(OFF, WB)                                                    \
    {                                                                    \
      const uint4 u = *(const uint4*)(ldsb + (OFF) + lbase);             \
      const float w = __int_as_float(WB);                                \
      const half2_t h0 = __builtin_bit_cast(half2_t, u.x);               \
      const half2_t h1 = __builtin_bit_cast(half2_t, u.y);               \
      const half2_t h2 = __builtin_bit_cast(half2_t, u.z);               \
      const half2_t h3 = __builtin_bit_cast(half2_t, u.w);               \
      a0 = fmaf(w, (float)h0.x, a0); a1 = fmaf(w, (float)h0.y, a1);      \
      a2 = fmaf(w, (float)h1.x, a2); a3 = fmaf(w, (float)h1.y, a3);      \
      a4 = fmaf(w, (float)h2.x, a4); a5 = fmaf(w, (float)h2.y, a5);      \
      a6 = fmaf(w, (float)h3.x, a6); a7 = fmaf(w, (float)h3.y, a7);      \
    }

    for (int q = 0; q < quads; ++q) {
      const int4 cA = pA, cB = pB;
      pA = e4[q * 2 + 2];  // max idx 49 < 52 int4 per padded row
      pB = e4[q * 2 + 3];
      PROC(cA.x, cA.y);
      PROC(cA.z, cA.w);
      PROC(cB.x, cB.y);
      PROC(cB.z, cB.w);
    }
#undef PROC

    const float b = bias[f];
    float4 o0, o1;
    o0.x = fmaxf(a0 + b, 0.f); o0.y = fmaxf(a1 + b, 0.f);
    o0.z = fmaxf(a2 + b, 0.f); o0.w = fmaxf(a3 + b, 0.f);
    o1.x = fmaxf(a4 + b, 0.f); o1.y = fmaxf(a5 + b, 0.f);
    o1.z = fmaxf(a6 + b, 0.f); o1.w = fmaxf(a7 + b, 0.f);
    float* op = out + (size_t)f * HW + hw0 + l8 * 8;
    *(float4*)op = o0;
    *(float4*)(op + 4) = o1;
  }
}

extern "C" void kernel_launch(void* const* d_in, const int* in_sizes, int n_in,
                              void* d_out, int out_size, void* d_ws, size_t ws_size,
                              hipStream_t stream) {
  const float* X = (const float*)d_in[0];     // (1, 512, 256, 256) fp32
  const float* kern = (const float*)d_in[1];  // (512, 512) fp32, pre-masked
  // d_in[2] = mask: redundant (kernel already zeroed where mask false)
  const float* bias = (const float*)d_in[3];  // (512,) fp32
  float* out = (float*)d_out;

  int2* ell = (int2*)d_ws;
  int* cnt = (int*)((char*)d_ws + (size_t)NF * ELL_STRIDE * sizeof(int2));

  prep_ell<<<NF * 64 / 256, 256, 0, stream>>>(kern, ell, cnt);
  spmm_main<<<HW / STRIP, 1024, 0, stream>>>(X, ell, cnt, bias, out);
}

// Round 5
// 318.883 us; speedup vs baseline: 1.4491x; 1.0336x over previous
//
#include <hip/hip_runtime.h>
#include <stdint.h>

// SparseConv2D: out[f, hw] = relu(sum_c K[f,c] * X[c, hw] + bias[f])
// F=C=512, HW=65536, K ~10% dense. ELL + nnz-sorted filter assignment +
// LDS-staged f16 X strips, v_fma_mix inner loop.
//
// R5: (a) ROWB back to 128 (R4's +16 pad DOUBLED conflicts: multi-row b128
// conflicts are structural, padding can't de-alias). (b) counting-sort filters
// by nnz desc; chunk of 8 rank-adjacent filters -> one (wave,fi) slot, so the
// 8 lane-groups have near-equal counts (max/mean ~1.02 vs 1.19) and the loop
// bound is one wave-uniform scalar chunkn[chunk].

#define NF 512
#define NC 512
#define HW 65536
#define ELL_CAP 96      // 6.6 sigma above mean row nnz (51.2, sd 6.8)
#define ELL_STRIDE 104  // int2 entries per row; 52 int4, 16B aligned
#define STRIP 64
#define ROWB 128        // f16 row bytes; NO pad (see R4 post-mortem)

typedef __fp16 half2_t __attribute__((ext_vector_type(2)));

__global__ __launch_bounds__(256) void prep_ell(const float* __restrict__ kernel,
                                                int2* __restrict__ ell,
                                                int* __restrict__ cnt) {
  const int row = (blockIdx.x * 256 + threadIdx.x) >> 6;  // one wave per filter
  const int lane = threadIdx.x & 63;
  if (row >= NF) return;
  const float* krow = kernel + (size_t)row * NC;
  int2* erow = ell + (size_t)row * ELL_STRIDE;
  int n = 0;
  for (int step = 0; step < NC / 64; ++step) {
    const int c = step * 64 + lane;
    const float w = krow[c];  // coalesced
    const bool nz = (w != 0.0f);
    const unsigned long long m = __ballot(nz);
    const int pos = n + __popcll(m & ((1ull << lane) - 1ull));
    if (nz && pos < ELL_CAP) erow[pos] = make_int2(c * ROWB, __float_as_int(w));
    n += __popcll(m);
  }
  const int nn = n < ELL_CAP ? n : ELL_CAP;
  // zero-pad tail: overrun iterations do fma * 0.0 on row 0 (finite) -> harmless
  for (int p = nn + lane; p < ELL_STRIDE; p += 64) erow[p] = make_int2(0, 0);
  if (lane == 0) cnt[row] = nn;
}

// Single block, 512 threads: descending counting sort of filters by nnz.
// perm[rank] = filter id; chunkn[j] = nnz of heaviest filter in chunk j.
__global__ __launch_bounds__(512) void prep_sort(const int* __restrict__ cnt,
                                                 int* __restrict__ perm,
                                                 int* __restrict__ chunkn) {
  __shared__ int base[ELL_CAP + 1];
  const int tid = threadIdx.x;
  if (tid <= ELL_CAP) base[tid] = 0;
  __syncthreads();
  const int c = cnt[tid];
  atomicAdd(&base[c], 1);
  __syncthreads();
  if (tid == 0) {  // exclusive prefix, descending keys (97 iters, trivial)
    int run = 0;
    for (int k = ELL_CAP; k >= 0; --k) { const int h = base[k]; base[k] = run; run += h; }
  }
  __syncthreads();
  const int rank = atomicAdd(&base[c], 1);  // stable-unique rank, desc by c
  perm[rank] = tid;
  __syncthreads();  // global writes by block visible after barrier
  if (tid < NF / 8) chunkn[tid] = cnt[perm[tid * 8]];  // first in chunk = max
}

__global__ __launch_bounds__(1024, 8) void spmm_main(
    const float* __restrict__ X, const int2* __restrict__ ell,
    const int* __restrict__ perm, const int* __restrict__ chunkn,
    const float* __restrict__ bias, float* __restrict__ out) {
  // 512 rows x 128B (64 f16) = 64 KiB -> 2 blocks/CU
  __shared__ __align__(16) char ldsb[NC * ROWB];

  const int tid = threadIdx.x;
  const int wave = tid >> 6;  // 0..15
  const int lane = tid & 63;
  const int hw0 = blockIdx.x * STRIP;

  // ---- stage: wave w loads rows [w*32, w*32+32); fp32 -> packed f16 (RTZ) ----
  {
    const int rsub = lane >> 4;        // 0..3
    const int colf = (lane & 15) * 4;  // float index within 64-wide row
    for (int i = 0; i < 8; ++i) {
      const int r = wave * 32 + i * 4 + rsub;
      const float4 x4 = *(const float4*)(X + (size_t)r * HW + hw0 + colf);
      const half2_t p0 = __builtin_amdgcn_cvt_pkrtz(x4.x, x4.y);
      const half2_t p1 = __builtin_amdgcn_cvt_pkrtz(x4.z, x4.w);
      uint2 p;
      p.x = __builtin_bit_cast(uint32_t, p0);
      p.y = __builtin_bit_cast(uint32_t, p1);
      *(uint2*)(ldsb + r * ROWB + colf * 2) = p;  // ds_write_b64, 8B aligned
    }
  }
  __syncthreads();

  // ---- compute: 8 groups of 8 lanes; chunk = 8 rank-adjacent filters ----
  const int l8 = lane & 7;
  const int g = lane >> 3;
  const int lbase = l8 * 16;  // byte offset in row: 8 f16 = hw [l8*8, l8*8+8)

  for (int fi = 0; fi < 4; ++fi) {
    const int chunk = fi * 16 + wave;       // wave-uniform
    const int f = perm[chunk * 8 + g];      // group-uniform filter id
    const int n = chunkn[chunk];            // wave-uniform bound (chunk max)
    const int quads = (n + 3) >> 2;
    const int4* e4 = (const int4*)(ell + (size_t)f * ELL_STRIDE);
    int4 pA = e4[0], pB = e4[1];  // 2 entries per int4; prefetch one quad ahead
    float a0 = 0.f, a1 = 0.f, a2 = 0.f, a3 = 0.f;
    float a4 = 0.f, a5 = 0.f, a6 = 0.f, a7 = 0.f;

#define PROC(OFF, WB)                                                    \
    {                                                                    \
      const uint4 u = *(const uint4*)(ldsb + (OFF) + lbase);             \
      const float w = __int_as_float(WB);                                \
      const half2_t h0 = __builtin_bit_cast(half2_t, u.x);               \
      const half2_t h1 = __builtin_bit_cast(half2_t, u.y);               \
      const half2_t h2 = __builtin_bit_cast(half2_t, u.z);               \
      const half2_t h3 = __builtin_bit_cast(half2_t, u.w);               \
      a0 = fmaf(w, (float)h0.x, a0); a1 = fmaf(w, (float)h0.y, a1);      \
      a2 = fmaf(w, (float)h1.x, a2); a3 = fmaf(w, (float)h1.y, a3);      \
      a4 = fmaf(w, (float)h2.x, a4); a5 = fmaf(w, (float)h2.y, a5);      \
      a6 = fmaf(w, (float)h3.x, a6); a7 = fmaf(w, (float)h3.y, a7);      \
    }

    for (int q = 0; q < quads; ++q) {
      const int4 cA = pA, cB = pB;
      pA = e4[q * 2 + 2];  // max idx 49 < 52 int4 per zero-padded row
      pB = e4[q * 2 + 3];
      PROC(cA.x, cA.y);
      PROC(cA.z, cA.w);
      PROC(cB.x, cB.y);
      PROC(cB.z, cB.w);
    }
#undef PROC

    const float b = bias[f];
    float4 o0, o1;
    o0.x = fmaxf(a0 + b, 0.f); o0.y = fmaxf(a1 + b, 0.f);
    o0.z = fmaxf(a2 + b, 0.f); o0.w = fmaxf(a3 + b, 0.f);
    o1.x = fmaxf(a4 + b, 0.f); o1.y = fmaxf(a5 + b, 0.f);
    o1.z = fmaxf(a6 + b, 0.f); o1.w = fmaxf(a7 + b, 0.f);
    float* op = out + (size_t)f * HW + hw0 + l8 * 8;  // 256B/group contiguous
    *(float4*)op = o0;
    *(float4*)(op + 4) = o1;
  }
}

extern "C" void kernel_launch(void* const* d_in, const int* in_sizes, int n_in,
                              void* d_out, int out_size, void* d_ws, size_t ws_size,
                              hipStream_t stream) {
  const float* X = (const float*)d_in[0];     // (1, 512, 256, 256) fp32
  const float* kern = (const float*)d_in[1];  // (512, 512) fp32, pre-masked
  // d_in[2] = mask: redundant (kernel already zeroed where mask false)
  const float* bias = (const float*)d_in[3];  // (512,) fp32
  float* out = (float*)d_out;

  char* ws = (char*)d_ws;
  int2* ell = (int2*)ws;                                   // 425984 B
  int* cnt = (int*)(ws + (size_t)NF * ELL_STRIDE * 8);     // 2 KB
  int* perm = cnt + NF;                                    // 2 KB
  int* chunkn = perm + NF;                                 // 256 B

  prep_ell<<<NF * 64 / 256, 256, 0, stream>>>(kern, ell, cnt);
  prep_sort<<<1, 512, 0, stream>>>(cnt, perm, chunkn);
  spmm_main<<<HW / STRIP, 1024, 0, stream>>>(X, ell, perm, chunkn, bias, out);
}